// Round 1
// baseline (3024.596 us; speedup 1.0000x reference)
//
#include <hip/hip_runtime.h>
#include <hip/hip_bf16.h>

#define HIDDEN  1024
#define FFN_DIM 2048
#define NEXP    8
#define NTOK    2048          // B*S = 2*1024
#define TT      12            // tokens per FFN tile (LDS-limited: 12*1024*4 + 12*256*4 = 60KB < 64KB)
#define FC      256           // ffn chunk width
#define NCHUNK  (FFN_DIM / FC)

// ---------------- Router: fp32 logits, softmax-top2, renormalized weights, expert binning ---------
__global__ __launch_bounds__(256) void router_kernel(
    const float* __restrict__ x, const float* __restrict__ gw,
    float* __restrict__ logits, int* __restrict__ cnt,
    int* __restrict__ tok, float* __restrict__ wgt)
{
  const int t   = blockIdx.x;
  const int tid = threadIdx.x;
  float4 xv = ((const float4*)(x + (size_t)t * HIDDEN))[tid];
  float p[NEXP];
#pragma unroll
  for (int e = 0; e < NEXP; ++e) {
    float4 gv = ((const float4*)(gw + (size_t)e * HIDDEN))[tid];
    p[e] = xv.x * gv.x + xv.y * gv.y + xv.z * gv.z + xv.w * gv.w;
  }
#pragma unroll
  for (int e = 0; e < NEXP; ++e) {
#pragma unroll
    for (int off = 32; off > 0; off >>= 1)
      p[e] += __shfl_down(p[e], off, 64);
  }
  __shared__ float red[4][NEXP];
  const int wv = tid >> 6, ln = tid & 63;
  if (ln == 0) {
#pragma unroll
    for (int e = 0; e < NEXP; ++e) red[wv][e] = p[e];
  }
  __syncthreads();
  if (tid == 0) {
    float l[NEXP];
#pragma unroll
    for (int e = 0; e < NEXP; ++e) {
      l[e] = red[0][e] + red[1][e] + red[2][e] + red[3][e];
      logits[(size_t)t * NEXP + e] = l[e];
    }
    // top-2 by logit (softmax is monotone); ties -> lowest index, matching jax.lax.top_k
    int i0 = 0;
#pragma unroll
    for (int e = 1; e < NEXP; ++e) if (l[e] > l[i0]) i0 = e;
    int i1 = (i0 == 0) ? 1 : 0;
#pragma unroll
    for (int e = 0; e < NEXP; ++e) if (e != i0 && l[e] > l[i1]) i1 = e;
    // renormalized top-2 softmax weights: w0 = e^l0/(e^l0+e^l1)
    float w0 = 1.f / (1.f + expf(l[i1] - l[i0]));
    float w1 = 1.f - w0;
    int s0 = atomicAdd(&cnt[i0], 1);
    tok[i0 * NTOK + s0] = t;  wgt[i0 * NTOK + s0] = w0;
    int s1 = atomicAdd(&cnt[i1], 1);
    tok[i1 * NTOK + s1] = t;  wgt[i1 * NTOK + s1] = w1;
  }
}

// ---------------- Fused expert FFN: h = silu(xW1^T)*(xW3^T); y = h W2^T; out += wgt*y ------------
__global__ __launch_bounds__(256) void moe_ffn_kernel(
    const float* __restrict__ x,
    const float* __restrict__ w1, const float* __restrict__ w2,
    const float* __restrict__ w3,
    const int* __restrict__ cnt, const int* __restrict__ tok,
    const float* __restrict__ wgt, float* __restrict__ out)
{
  const int e  = blockIdx.y;
  const int n  = cnt[e];
  const int ts = blockIdx.x * TT;
  if (ts >= n) return;
  const int tid = threadIdx.x;

  __shared__ float xs[TT * HIDDEN];   // 48 KB
  __shared__ float hc[TT * FC];       // 12 KB
  __shared__ int   stok[TT];
  __shared__ float swgt[TT];

  if (tid < TT) {
    int idx = ts + tid;
    int tk  = (idx < n) ? tok[e * NTOK + idx] : -1;
    stok[tid] = tk;
    swgt[tid] = (idx < n) ? wgt[e * NTOK + idx] : 0.f;
  }
  __syncthreads();
#pragma unroll
  for (int i = 0; i < TT; ++i) {
    int tk = stok[i];
    float4 v = make_float4(0.f, 0.f, 0.f, 0.f);
    if (tk >= 0) v = ((const float4*)(x + (size_t)tk * HIDDEN))[tid];
    ((float4*)(xs + i * HIDDEN))[tid] = v;
  }
  __syncthreads();

  const float* w1e = w1 + (size_t)e * FFN_DIM * HIDDEN;
  const float* w3e = w3 + (size_t)e * FFN_DIM * HIDDEN;
  const float* w2e = w2 + (size_t)e * HIDDEN * FFN_DIM;

  float yacc[4][TT];
#pragma unroll
  for (int j = 0; j < 4; ++j)
#pragma unroll
    for (int t = 0; t < TT; ++t) yacc[j][t] = 0.f;

  for (int c = 0; c < NCHUNK; ++c) {
    // ---- h chunk: each thread owns one ffn row f
    const int f = c * FC + tid;
    const float4* r1 = (const float4*)(w1e + (size_t)f * HIDDEN);
    const float4* r3 = (const float4*)(w3e + (size_t)f * HIDDEN);
    float a1[TT], a3[TT];
#pragma unroll
    for (int t = 0; t < TT; ++t) { a1[t] = 0.f; a3[t] = 0.f; }
    for (int k = 0; k < HIDDEN / 4; ++k) {
      float4 v1 = r1[k];
      float4 v3 = r3[k];
#pragma unroll
      for (int t = 0; t < TT; ++t) {
        float4 xv = *(const float4*)(xs + t * HIDDEN + 4 * k);  // wave-broadcast LDS read
        a1[t] += xv.x * v1.x + xv.y * v1.y + xv.z * v1.z + xv.w * v1.w;
        a3[t] += xv.x * v3.x + xv.y * v3.y + xv.z * v3.z + xv.w * v3.w;
      }
    }
    __syncthreads();   // previous chunk's hc readers done
#pragma unroll
    for (int t = 0; t < TT; ++t) {
      float g  = a1[t];
      float sg = g / (1.f + __expf(-g));   // silu
      hc[t * FC + tid] = sg * a3[t];
    }
    __syncthreads();
    // ---- y partial: each thread owns 4 output dims d = tid + {0,256,512,768}
    const float4* r20 = (const float4*)(w2e + (size_t)(tid      ) * FFN_DIM + c * FC);
    const float4* r21 = (const float4*)(w2e + (size_t)(tid + 256) * FFN_DIM + c * FC);
    const float4* r22 = (const float4*)(w2e + (size_t)(tid + 512) * FFN_DIM + c * FC);
    const float4* r23 = (const float4*)(w2e + (size_t)(tid + 768) * FFN_DIM + c * FC);
    for (int k = 0; k < FC / 4; ++k) {
      float4 wv0 = r20[k], wv1 = r21[k], wv2 = r22[k], wv3 = r23[k];
#pragma unroll
      for (int t = 0; t < TT; ++t) {
        float4 hv = *(const float4*)(hc + t * FC + 4 * k);      // wave-broadcast LDS read
        yacc[0][t] += hv.x * wv0.x + hv.y * wv0.y + hv.z * wv0.z + hv.w * wv0.w;
        yacc[1][t] += hv.x * wv1.x + hv.y * wv1.y + hv.z * wv1.z + hv.w * wv1.w;
        yacc[2][t] += hv.x * wv2.x + hv.y * wv2.y + hv.z * wv2.z + hv.w * wv2.w;
        yacc[3][t] += hv.x * wv3.x + hv.y * wv3.y + hv.z * wv3.z + hv.w * wv3.w;
      }
    }
  }

  // ---- weighted combine (2 atomic adds per out element total across the grid)
#pragma unroll
  for (int t = 0; t < TT; ++t) {
    int tk = stok[t];
    if (tk < 0) continue;
    float wt = swgt[t];
    float* orow = out + (size_t)tk * HIDDEN;
    atomicAdd(orow + tid,       wt * yacc[0][t]);
    atomicAdd(orow + tid + 256, wt * yacc[1][t]);
    atomicAdd(orow + tid + 512, wt * yacc[2][t]);
    atomicAdd(orow + tid + 768, wt * yacc[3][t]);
  }
}

extern "C" void kernel_launch(void* const* d_in, const int* in_sizes, int n_in,
                              void* d_out, int out_size, void* d_ws, size_t ws_size,
                              hipStream_t stream) {
  const float* x  = (const float*)d_in[0];
  const float* gw = (const float*)d_in[1];
  const float* w1 = (const float*)d_in[2];
  const float* w2 = (const float*)d_in[3];
  const float* w3 = (const float*)d_in[4];
  float* out    = (float*)d_out;
  float* logits = out + (size_t)NTOK * HIDDEN;   // outputs concat: [out | router_logits]

  char*  ws  = (char*)d_ws;                      // ws usage: 64 + 64KB + 64KB  (~131KB, safe)
  int*   cnt = (int*)ws;
  int*   tok = (int*)(ws + 64);
  float* wgt = (float*)(ws + 64 + NEXP * NTOK * sizeof(int));

  hipMemsetAsync(out, 0, (size_t)NTOK * HIDDEN * sizeof(float), stream);  // atomic accum target
  hipMemsetAsync(cnt, 0, NEXP * sizeof(int), stream);

  router_kernel<<<NTOK, 256, 0, stream>>>(x, gw, logits, cnt, tok, wgt);

  dim3 grid((NTOK + TT - 1) / TT, NEXP);
  moe_ffn_kernel<<<grid, 256, 0, stream>>>(x, w1, w2, w3, cnt, tok, wgt, out);
}

// Round 2
// 480.656 us; speedup vs baseline: 6.2926x; 6.2926x over previous
//
#include <hip/hip_runtime.h>
#include <hip/hip_bf16.h>
#include <stdint.h>

#define HIDDEN  1024
#define FFN_DIM 2048
#define NEXP    8
#define NTOK    2048          // B*S
#define MAXROWS 5120          // sum of 128-padded per-expert counts <= 4096 + 8*127

typedef short bf16x8 __attribute__((ext_vector_type(8)));
typedef float f32x4  __attribute__((ext_vector_type(4)));

// ---------------- ws layout (bytes) ----------------
static const size_t OFF_CNT  = 0;                         // 8 ints
static const size_t OFF_BASE = 64;                        // 9 ints
static const size_t OFF_TOK  = 128;                       // 8*2048 ints
static const size_t OFF_WGT  = OFF_TOK + (size_t)NEXP*NTOK*4;
static const size_t OFF_XBF  = 131328;                    // 256-aligned
static const size_t XBF_B    = (size_t)NTOK*HIDDEN*2;
static const size_t OFF_W1B  = OFF_XBF + XBF_B;
static const size_t W_B      = (size_t)NEXP*FFN_DIM*HIDDEN*2;
static const size_t OFF_W3B  = OFF_W1B + W_B;
static const size_t OFF_W2B  = OFF_W3B + W_B;
static const size_t OFF_H    = OFF_W2B + W_B;
static const size_t H_B      = (size_t)MAXROWS*FFN_DIM*2;
static const size_t WS_NEED  = OFF_H + H_B;               // ~126 MB

__device__ __forceinline__ unsigned short f2bf(float f) {
  union { float f; unsigned u; } a; a.f = f;
  unsigned r = a.u + 0x7fff + ((a.u >> 16) & 1);          // RTN-even
  return (unsigned short)(r >> 16);
}

__device__ __forceinline__ void ld_g2l16(const void* gsrc, void* ldst) {
  __builtin_amdgcn_global_load_lds(
      (const __attribute__((address_space(1))) unsigned int*)gsrc,
      (__attribute__((address_space(3))) unsigned int*)ldst, 16, 0, 0);
}

// ---------------- Router: fp32-exact logits, top-2, renorm weights, expert bins ----------------
__global__ __launch_bounds__(256) void router_kernel(
    const float* __restrict__ x, const float* __restrict__ gw,
    float* __restrict__ logits, int* __restrict__ cnt,
    int* __restrict__ tok, float* __restrict__ wgt)
{
  const int t   = blockIdx.x;
  const int tid = threadIdx.x;
  float4 xv = ((const float4*)(x + (size_t)t * HIDDEN))[tid];
  float p[NEXP];
#pragma unroll
  for (int e = 0; e < NEXP; ++e) {
    float4 gv = ((const float4*)(gw + (size_t)e * HIDDEN))[tid];
    p[e] = xv.x * gv.x + xv.y * gv.y + xv.z * gv.z + xv.w * gv.w;
  }
#pragma unroll
  for (int e = 0; e < NEXP; ++e) {
#pragma unroll
    for (int off = 32; off > 0; off >>= 1)
      p[e] += __shfl_down(p[e], off, 64);
  }
  __shared__ float red[4][NEXP];
  const int wv = tid >> 6, ln = tid & 63;
  if (ln == 0) {
#pragma unroll
    for (int e = 0; e < NEXP; ++e) red[wv][e] = p[e];
  }
  __syncthreads();
  if (tid == 0) {
    float l[NEXP];
#pragma unroll
    for (int e = 0; e < NEXP; ++e) {
      l[e] = red[0][e] + red[1][e] + red[2][e] + red[3][e];
      logits[(size_t)t * NEXP + e] = l[e];
    }
    int i0 = 0;
#pragma unroll
    for (int e = 1; e < NEXP; ++e) if (l[e] > l[i0]) i0 = e;
    int i1 = (i0 == 0) ? 1 : 0;
#pragma unroll
    for (int e = 0; e < NEXP; ++e) if (e != i0 && l[e] > l[i1]) i1 = e;
    float w0 = 1.f / (1.f + expf(l[i1] - l[i0]));
    float w1 = 1.f - w0;
    int s0 = atomicAdd(&cnt[i0], 1);
    tok[i0 * NTOK + s0] = t;  wgt[i0 * NTOK + s0] = w0;
    int s1 = atomicAdd(&cnt[i1], 1);
    tok[i1 * NTOK + s1] = t;  wgt[i1 * NTOK + s1] = w1;
  }
}

// ---------------- 128-padded per-expert row bases ----------------
__global__ void prefix_kernel(const int* __restrict__ cnt, int* __restrict__ base) {
  if (threadIdx.x == 0 && blockIdx.x == 0) {
    int b = 0;
#pragma unroll
    for (int e = 0; e < NEXP; ++e) { base[e] = b; b += ((cnt[e] + 127) >> 7) << 7; }
    base[NEXP] = b;
  }
}

// ---------------- fp32 -> bf16 conversion ----------------
__global__ __launch_bounds__(256) void cvt_kernel(
    const float* __restrict__ src, unsigned short* __restrict__ dst, int n4)
{
  int i = blockIdx.x * blockDim.x + threadIdx.x;
  const int stride = gridDim.x * blockDim.x;
  for (; i < n4; i += stride) {
    float4 v = ((const float4*)src)[i];
    ushort4 o;
    o.x = f2bf(v.x); o.y = f2bf(v.y); o.z = f2bf(v.z); o.w = f2bf(v.w);
    ((ushort4*)dst)[i] = o;
  }
}

// ---------------- GEMM1: H = silu(X W1^T) * (X W3^T), bf16 MFMA, m97 2-barrier ----------------
__global__ __launch_bounds__(512) void gemm1_kernel(
    const unsigned short* __restrict__ xbf,   // [NTOK][HIDDEN]
    const unsigned short* __restrict__ w1bf,  // [E][FFN][HIDDEN]
    const unsigned short* __restrict__ w3bf,
    const int* __restrict__ cnt, const int* __restrict__ base,
    const int* __restrict__ tok,
    unsigned short* __restrict__ H)           // [MAXROWS][FFN]
{
  const int mt = blockIdx.x, nt = blockIdx.y, e = blockIdx.z;
  const int n = cnt[e];
  if (mt * 128 >= n) return;
  const int t = threadIdx.x;
  const int w = t >> 6, l = t & 63;

  __shared__ unsigned short Xs [128 * 64];
  __shared__ unsigned short W1s[128 * 64];
  __shared__ unsigned short W3s[128 * 64];
  __shared__ int stok[128];

  if (t < 128) {
    int idx = mt * 128 + t;
    stok[t] = tok[e * NTOK + min(idx, n - 1)];   // pad rows: duplicate last (masked later)
  }
  __syncthreads();

  const int r0 = t >> 3;                 // staged row for issue 0 (issue 1: +64)
  const size_t tok0 = (size_t)stok[r0];
  const size_t tok1 = (size_t)stok[64 + r0];
  const int kpart = (t & 7) * 8;         // k-element offset within 64-wide tile

  const unsigned short* w1e = w1bf + (size_t)e * FFN_DIM * HIDDEN + (size_t)(nt * 128) * HIDDEN;
  const unsigned short* w3e = w3bf + (size_t)e * FFN_DIM * HIDDEN + (size_t)(nt * 128) * HIDDEN;

  f32x4 acc1[4][2], acc3[4][2];
#pragma unroll
  for (int i = 0; i < 4; ++i)
#pragma unroll
    for (int j = 0; j < 2; ++j) { acc1[i][j] = (f32x4)0.f; acc3[i][j] = (f32x4)0.f; }

  const int Moff = (w & 1) * 64;
  const int Noff = (w >> 1) * 32;
  char* ldsX = (char*)Xs  + w * 1024;    // wave-uniform dest bases (lane adds l*16)
  char* ldsA = (char*)W1s + w * 1024;
  char* ldsB = (char*)W3s + w * 1024;

  for (int kb = 0; kb < HIDDEN / 64; ++kb) {
    __syncthreads();                     // previous compute done with LDS
    const int kofs = kb * 64 + kpart;
    ld_g2l16(xbf + tok0 * HIDDEN + kofs,               ldsX);
    ld_g2l16(xbf + tok1 * HIDDEN + kofs,               ldsX + 8192);
    ld_g2l16(w1e + (size_t)r0 * HIDDEN + kofs,         ldsA);
    ld_g2l16(w1e + (size_t)(64 + r0) * HIDDEN + kofs,  ldsA + 8192);
    ld_g2l16(w3e + (size_t)r0 * HIDDEN + kofs,         ldsB);
    ld_g2l16(w3e + (size_t)(64 + r0) * HIDDEN + kofs,  ldsB + 8192);
    __syncthreads();                     // compiler drains vmcnt before s_barrier
#pragma unroll
    for (int s = 0; s < 2; ++s) {
      const int ke = s * 32 + (l >> 4) * 8;
      bf16x8 a[4], b1[2], b3[2];
#pragma unroll
      for (int mi = 0; mi < 4; ++mi)
        a[mi] = *(const bf16x8*)&Xs[(Moff + mi * 16 + (l & 15)) * 64 + ke];
#pragma unroll
      for (int ni = 0; ni < 2; ++ni) {
        b1[ni] = *(const bf16x8*)&W1s[(Noff + ni * 16 + (l & 15)) * 64 + ke];
        b3[ni] = *(const bf16x8*)&W3s[(Noff + ni * 16 + (l & 15)) * 64 + ke];
      }
#pragma unroll
      for (int mi = 0; mi < 4; ++mi)
#pragma unroll
        for (int ni = 0; ni < 2; ++ni) {
          acc1[mi][ni] = __builtin_amdgcn_mfma_f32_16x16x32_bf16(a[mi], b1[ni], acc1[mi][ni], 0, 0, 0);
          acc3[mi][ni] = __builtin_amdgcn_mfma_f32_16x16x32_bf16(a[mi], b3[ni], acc3[mi][ni], 0, 0, 0);
        }
    }
  }

  const size_t rbase = (size_t)base[e] + (size_t)mt * 128;
#pragma unroll
  for (int mi = 0; mi < 4; ++mi)
#pragma unroll
    for (int ni = 0; ni < 2; ++ni)
#pragma unroll
      for (int j = 0; j < 4; ++j) {
        int row = Moff + mi * 16 + (l >> 4) * 4 + j;
        int col = nt * 128 + Noff + ni * 16 + (l & 15);
        float s1 = acc1[mi][ni][j], s3 = acc3[mi][ni][j];
        float h = (s1 / (1.f + __expf(-s1))) * s3;      // silu(s1)*s3
        H[(rbase + row) * FFN_DIM + col] = f2bf(h);
      }
}

// ---------------- GEMM2: Y = H W2^T, scale by routing weight, atomicAdd into out ----------------
__global__ __launch_bounds__(512) void gemm2_kernel(
    const unsigned short* __restrict__ H,
    const unsigned short* __restrict__ w2bf,  // [E][HIDDEN][FFN]
    const int* __restrict__ cnt, const int* __restrict__ base,
    const int* __restrict__ tok, const float* __restrict__ wgt,
    float* __restrict__ out)
{
  const int mt = blockIdx.x, nt = blockIdx.y, e = blockIdx.z;
  const int n = cnt[e];
  if (mt * 128 >= n) return;
  const int t = threadIdx.x;
  const int w = t >> 6, l = t & 63;

  __shared__ unsigned short Hs[128 * 64];
  __shared__ unsigned short Ws[128 * 64];
  __shared__ int   stok[128];
  __shared__ float swgt[128];

  if (t < 128) {
    int idx = mt * 128 + t;
    int ok = idx < n;
    stok[t] = ok ? tok[e * NTOK + idx] : -1;
    swgt[t] = ok ? wgt[e * NTOK + idx] : 0.f;
  }

  const int r0 = t >> 3;
  const int kpart = (t & 7) * 8;
  const unsigned short* He  = H + (size_t)(base[e] + mt * 128) * FFN_DIM;
  const unsigned short* w2e = w2bf + (size_t)e * HIDDEN * FFN_DIM + (size_t)(nt * 128) * FFN_DIM;

  f32x4 acc[4][2];
#pragma unroll
  for (int i = 0; i < 4; ++i)
#pragma unroll
    for (int j = 0; j < 2; ++j) acc[i][j] = (f32x4)0.f;

  const int Moff = (w & 1) * 64;
  const int Noff = (w >> 1) * 32;
  char* ldsH = (char*)Hs + w * 1024;
  char* ldsW = (char*)Ws + w * 1024;

  for (int kb = 0; kb < FFN_DIM / 64; ++kb) {
    __syncthreads();
    const int kofs = kb * 64 + kpart;
    ld_g2l16(He  + (size_t)r0 * FFN_DIM + kofs,        ldsH);
    ld_g2l16(He  + (size_t)(64 + r0) * FFN_DIM + kofs, ldsH + 8192);
    ld_g2l16(w2e + (size_t)r0 * FFN_DIM + kofs,        ldsW);
    ld_g2l16(w2e + (size_t)(64 + r0) * FFN_DIM + kofs, ldsW + 8192);
    __syncthreads();
#pragma unroll
    for (int s = 0; s < 2; ++s) {
      const int ke = s * 32 + (l >> 4) * 8;
      bf16x8 a[4], b[2];
#pragma unroll
      for (int mi = 0; mi < 4; ++mi)
        a[mi] = *(const bf16x8*)&Hs[(Moff + mi * 16 + (l & 15)) * 64 + ke];
#pragma unroll
      for (int ni = 0; ni < 2; ++ni)
        b[ni] = *(const bf16x8*)&Ws[(Noff + ni * 16 + (l & 15)) * 64 + ke];
#pragma unroll
      for (int mi = 0; mi < 4; ++mi)
#pragma unroll
        for (int ni = 0; ni < 2; ++ni)
          acc[mi][ni] = __builtin_amdgcn_mfma_f32_16x16x32_bf16(a[mi], b[ni], acc[mi][ni], 0, 0, 0);
    }
  }

#pragma unroll
  for (int mi = 0; mi < 4; ++mi)
#pragma unroll
    for (int ni = 0; ni < 2; ++ni)
#pragma unroll
      for (int j = 0; j < 4; ++j) {
        int row = Moff + mi * 16 + (l >> 4) * 4 + j;
        int tk = stok[row];
        if (tk >= 0) {
          int col = nt * 128 + Noff + ni * 16 + (l & 15);
          atomicAdd(&out[(size_t)tk * HIDDEN + col], swgt[row] * acc[mi][ni][j]);
        }
      }
}

// ================= fp32 fallback path (round-1, used only if ws too small) =================
#define TT 12
#define FC 256
#define NCHUNK (FFN_DIM / FC)

__global__ __launch_bounds__(256) void moe_ffn_kernel(
    const float* __restrict__ x,
    const float* __restrict__ w1, const float* __restrict__ w2,
    const float* __restrict__ w3,
    const int* __restrict__ cnt, const int* __restrict__ tok,
    const float* __restrict__ wgt, float* __restrict__ out)
{
  const int e  = blockIdx.y;
  const int n  = cnt[e];
  const int ts = blockIdx.x * TT;
  if (ts >= n) return;
  const int tid = threadIdx.x;

  __shared__ float xs[TT * HIDDEN];
  __shared__ float hc[TT * FC];
  __shared__ int   stok[TT];
  __shared__ float swgt[TT];

  if (tid < TT) {
    int idx = ts + tid;
    int tk  = (idx < n) ? tok[e * NTOK + idx] : -1;
    stok[tid] = tk;
    swgt[tid] = (idx < n) ? wgt[e * NTOK + idx] : 0.f;
  }
  __syncthreads();
#pragma unroll
  for (int i = 0; i < TT; ++i) {
    int tk = stok[i];
    float4 v = make_float4(0.f, 0.f, 0.f, 0.f);
    if (tk >= 0) v = ((const float4*)(x + (size_t)tk * HIDDEN))[tid];
    ((float4*)(xs + i * HIDDEN))[tid] = v;
  }
  __syncthreads();

  const float* w1e = w1 + (size_t)e * FFN_DIM * HIDDEN;
  const float* w3e = w3 + (size_t)e * FFN_DIM * HIDDEN;
  const float* w2e = w2 + (size_t)e * HIDDEN * FFN_DIM;

  float yacc[4][TT];
#pragma unroll
  for (int j = 0; j < 4; ++j)
#pragma unroll
    for (int t = 0; t < TT; ++t) yacc[j][t] = 0.f;

  for (int c = 0; c < NCHUNK; ++c) {
    const int f = c * FC + tid;
    const float4* r1 = (const float4*)(w1e + (size_t)f * HIDDEN);
    const float4* r3 = (const float4*)(w3e + (size_t)f * HIDDEN);
    float a1[TT], a3[TT];
#pragma unroll
    for (int t = 0; t < TT; ++t) { a1[t] = 0.f; a3[t] = 0.f; }
    for (int k = 0; k < HIDDEN / 4; ++k) {
      float4 v1 = r1[k];
      float4 v3 = r3[k];
#pragma unroll
      for (int t = 0; t < TT; ++t) {
        float4 xv = *(const float4*)(xs + t * HIDDEN + 4 * k);
        a1[t] += xv.x * v1.x + xv.y * v1.y + xv.z * v1.z + xv.w * v1.w;
        a3[t] += xv.x * v3.x + xv.y * v3.y + xv.z * v3.z + xv.w * v3.w;
      }
    }
    __syncthreads();
#pragma unroll
    for (int t = 0; t < TT; ++t) {
      float g  = a1[t];
      float sg = g / (1.f + __expf(-g));
      hc[t * FC + tid] = sg * a3[t];
    }
    __syncthreads();
    const float4* r20 = (const float4*)(w2e + (size_t)(tid      ) * FFN_DIM + c * FC);
    const float4* r21 = (const float4*)(w2e + (size_t)(tid + 256) * FFN_DIM + c * FC);
    const float4* r22 = (const float4*)(w2e + (size_t)(tid + 512) * FFN_DIM + c * FC);
    const float4* r23 = (const float4*)(w2e + (size_t)(tid + 768) * FFN_DIM + c * FC);
    for (int k = 0; k < FC / 4; ++k) {
      float4 wv0 = r20[k], wv1 = r21[k], wv2 = r22[k], wv3 = r23[k];
#pragma unroll
      for (int t = 0; t < TT; ++t) {
        float4 hv = *(const float4*)(hc + t * FC + 4 * k);
        yacc[0][t] += hv.x * wv0.x + hv.y * wv0.y + hv.z * wv0.z + hv.w * wv0.w;
        yacc[1][t] += hv.x * wv1.x + hv.y * wv1.y + hv.z * wv1.z + hv.w * wv1.w;
        yacc[2][t] += hv.x * wv2.x + hv.y * wv2.y + hv.z * wv2.z + hv.w * wv2.w;
        yacc[3][t] += hv.x * wv3.x + hv.y * wv3.y + hv.z * wv3.z + hv.w * wv3.w;
      }
    }
  }

#pragma unroll
  for (int t = 0; t < TT; ++t) {
    int tk = stok[t];
    if (tk < 0) continue;
    float wt = swgt[t];
    float* orow = out + (size_t)tk * HIDDEN;
    atomicAdd(orow + tid,       wt * yacc[0][t]);
    atomicAdd(orow + tid + 256, wt * yacc[1][t]);
    atomicAdd(orow + tid + 512, wt * yacc[2][t]);
    atomicAdd(orow + tid + 768, wt * yacc[3][t]);
  }
}

extern "C" void kernel_launch(void* const* d_in, const int* in_sizes, int n_in,
                              void* d_out, int out_size, void* d_ws, size_t ws_size,
                              hipStream_t stream) {
  const float* x  = (const float*)d_in[0];
  const float* gw = (const float*)d_in[1];
  const float* w1 = (const float*)d_in[2];
  const float* w2 = (const float*)d_in[3];
  const float* w3 = (const float*)d_in[4];
  float* out    = (float*)d_out;
  float* logits = out + (size_t)NTOK * HIDDEN;

  char* ws = (char*)d_ws;
  int*   cnt  = (int*)(ws + OFF_CNT);
  int*   base = (int*)(ws + OFF_BASE);
  int*   tokp = (int*)(ws + OFF_TOK);
  float* wgtp = (float*)(ws + OFF_WGT);

  hipMemsetAsync(out, 0, (size_t)NTOK * HIDDEN * sizeof(float), stream);
  hipMemsetAsync(cnt, 0, NEXP * sizeof(int), stream);

  router_kernel<<<NTOK, 256, 0, stream>>>(x, gw, logits, cnt, tokp, wgtp);

  if (ws_size >= WS_NEED) {
    unsigned short* xbf  = (unsigned short*)(ws + OFF_XBF);
    unsigned short* w1bf = (unsigned short*)(ws + OFF_W1B);
    unsigned short* w3bf = (unsigned short*)(ws + OFF_W3B);
    unsigned short* w2bf = (unsigned short*)(ws + OFF_W2B);
    unsigned short* Hbuf = (unsigned short*)(ws + OFF_H);

    cvt_kernel<<<1024, 256, 0, stream>>>(x,  xbf,  (int)(NTOK * HIDDEN / 4));
    cvt_kernel<<<2048, 256, 0, stream>>>(w1, w1bf, (int)(NEXP * FFN_DIM * HIDDEN / 4));
    cvt_kernel<<<2048, 256, 0, stream>>>(w3, w3bf, (int)(NEXP * FFN_DIM * HIDDEN / 4));
    cvt_kernel<<<2048, 256, 0, stream>>>(w2, w2bf, (int)(NEXP * HIDDEN * FFN_DIM / 4));

    prefix_kernel<<<1, 64, 0, stream>>>(cnt, base);

    dim3 g1(NTOK / 128, FFN_DIM / 128, NEXP);   // 16 x 16 x 8, inactive tiles exit
    gemm1_kernel<<<g1, 512, 0, stream>>>(xbf, w1bf, w3bf, cnt, base, tokp, Hbuf);

    dim3 g2(NTOK / 128, HIDDEN / 128, NEXP);    // 16 x 8 x 8
    gemm2_kernel<<<g2, 512, 0, stream>>>(Hbuf, w2bf, cnt, base, tokp, wgtp, out);
  } else {
    dim3 grid((NTOK + TT - 1) / TT, NEXP);
    moe_ffn_kernel<<<grid, 256, 0, stream>>>(x, w1, w2, w3, cnt, tokp, wgtp, out);
  }
}

// Round 3
// 218.344 us; speedup vs baseline: 13.8524x; 2.2014x over previous
//
#include <hip/hip_runtime.h>
#include <hip/hip_bf16.h>
#include <stdint.h>

#define HIDDEN  1024
#define FFN_DIM 2048
#define NEXP    8
#define NTOK    2048          // B*S
#define MAXROWS 5120          // sum of 128-padded per-expert counts

typedef short bf16x8 __attribute__((ext_vector_type(8)));
typedef float f32x4  __attribute__((ext_vector_type(4)));

// ---------------- ws layout (bytes) ----------------
static const size_t OFF_CNT  = 0;                         // 8 ints
static const size_t OFF_BASE = 64;                        // 9 ints
static const size_t OFF_TOK  = 128;                       // 8*2048 ints
static const size_t OFF_WGT  = OFF_TOK + (size_t)NEXP*NTOK*4;
static const size_t OFF_XBF  = 131328;                    // 256-aligned
static const size_t XBF_B    = (size_t)NTOK*HIDDEN*2;
static const size_t OFF_W1B  = OFF_XBF + XBF_B;
static const size_t W_B      = (size_t)NEXP*FFN_DIM*HIDDEN*2;
static const size_t OFF_W3B  = OFF_W1B + W_B;
static const size_t OFF_W2B  = OFF_W3B + W_B;
static const size_t OFF_H    = OFF_W2B + W_B;
static const size_t H_B      = (size_t)MAXROWS*FFN_DIM*2;
static const size_t WS_NEED  = OFF_H + H_B;               // ~126 MB

__device__ __forceinline__ unsigned short f2bf(float f) {
  union { float f; unsigned u; } a; a.f = f;
  unsigned r = a.u + 0x7fff + ((a.u >> 16) & 1);          // RTN-even
  return (unsigned short)(r >> 16);
}

__device__ __forceinline__ void ld_g2l16(const void* gsrc, void* ldst) {
  __builtin_amdgcn_global_load_lds(
      (const __attribute__((address_space(1))) unsigned int*)gsrc,
      (__attribute__((address_space(3))) unsigned int*)ldst, 16, 0, 0);
}

// ---------------- Router: fp32-exact logits, top-2, renorm weights, expert bins ----------------
__global__ __launch_bounds__(256) void router_kernel(
    const float* __restrict__ x, const float* __restrict__ gw,
    float* __restrict__ logits, int* __restrict__ cnt,
    int* __restrict__ tok, float* __restrict__ wgt)
{
  const int t   = blockIdx.x;
  const int tid = threadIdx.x;
  float4 xv = ((const float4*)(x + (size_t)t * HIDDEN))[tid];
  float p[NEXP];
#pragma unroll
  for (int e = 0; e < NEXP; ++e) {
    float4 gv = ((const float4*)(gw + (size_t)e * HIDDEN))[tid];
    p[e] = xv.x * gv.x + xv.y * gv.y + xv.z * gv.z + xv.w * gv.w;
  }
#pragma unroll
  for (int e = 0; e < NEXP; ++e) {
#pragma unroll
    for (int off = 32; off > 0; off >>= 1)
      p[e] += __shfl_down(p[e], off, 64);
  }
  __shared__ float red[4][NEXP];
  const int wv = tid >> 6, ln = tid & 63;
  if (ln == 0) {
#pragma unroll
    for (int e = 0; e < NEXP; ++e) red[wv][e] = p[e];
  }
  __syncthreads();
  if (tid == 0) {
    float l[NEXP];
#pragma unroll
    for (int e = 0; e < NEXP; ++e) {
      l[e] = red[0][e] + red[1][e] + red[2][e] + red[3][e];
      logits[(size_t)t * NEXP + e] = l[e];
    }
    int i0 = 0;
#pragma unroll
    for (int e = 1; e < NEXP; ++e) if (l[e] > l[i0]) i0 = e;
    int i1 = (i0 == 0) ? 1 : 0;
#pragma unroll
    for (int e = 0; e < NEXP; ++e) if (e != i0 && l[e] > l[i1]) i1 = e;
    float w0 = 1.f / (1.f + expf(l[i1] - l[i0]));
    float w1 = 1.f - w0;
    int s0 = atomicAdd(&cnt[i0], 1);
    tok[i0 * NTOK + s0] = t;  wgt[i0 * NTOK + s0] = w0;
    int s1 = atomicAdd(&cnt[i1], 1);
    tok[i1 * NTOK + s1] = t;  wgt[i1 * NTOK + s1] = w1;
  }
}

// ---------------- 128-padded per-expert row bases ----------------
__global__ void prefix_kernel(const int* __restrict__ cnt, int* __restrict__ base) {
  if (threadIdx.x == 0 && blockIdx.x == 0) {
    int b = 0;
#pragma unroll
    for (int e = 0; e < NEXP; ++e) { base[e] = b; b += ((cnt[e] + 127) >> 7) << 7; }
    base[NEXP] = b;
  }
}

// ---------------- fp32 -> bf16 conversion (x) ----------------
__global__ __launch_bounds__(256) void cvt_kernel(
    const float* __restrict__ src, unsigned short* __restrict__ dst, int n4)
{
  int i = blockIdx.x * blockDim.x + threadIdx.x;
  const int stride = gridDim.x * blockDim.x;
  for (; i < n4; i += stride) {
    float4 v = ((const float4*)src)[i];
    ushort4 o;
    o.x = f2bf(v.x); o.y = f2bf(v.y); o.z = f2bf(v.z); o.w = f2bf(v.w);
    ((ushort4*)dst)[i] = o;
  }
}

// ---------------- fp32 -> bf16 conversion, 3 equal-size tensors in one launch ----------------
__global__ __launch_bounds__(256) void cvt3_kernel(
    const float* __restrict__ s0, const float* __restrict__ s1, const float* __restrict__ s2,
    unsigned short* __restrict__ d0, unsigned short* __restrict__ d1, unsigned short* __restrict__ d2,
    int n4)
{
  const int start  = blockIdx.x * blockDim.x + threadIdx.x;
  const int stride = gridDim.x * blockDim.x;
#pragma unroll
  for (int pass = 0; pass < 3; ++pass) {
    const float* s = (pass == 0) ? s0 : (pass == 1) ? s1 : s2;
    unsigned short* d = (pass == 0) ? d0 : (pass == 1) ? d1 : d2;
    for (int i = start; i < n4; i += stride) {
      float4 v = ((const float4*)s)[i];
      ushort4 o;
      o.x = f2bf(v.x); o.y = f2bf(v.y); o.z = f2bf(v.z); o.w = f2bf(v.w);
      ((ushort4*)d)[i] = o;
    }
  }
}

// ---------------- GEMM1: H = silu(X W1^T) * (X W3^T), bf16 MFMA ----------------
// LDS layout: [128 rows][8 units of 16B]; unit u_l of row r holds global unit (u_l ^ (r&7)).
// Staged via linear global_load_lds with pre-swizzled global source; reads XOR the same key.
__global__ __launch_bounds__(512) void gemm1_kernel(
    const unsigned short* __restrict__ xbf,   // [NTOK][HIDDEN]
    const unsigned short* __restrict__ w1bf,  // [E][FFN][HIDDEN]
    const unsigned short* __restrict__ w3bf,
    const int* __restrict__ cnt, const int* __restrict__ base,
    const int* __restrict__ tok,
    unsigned short* __restrict__ H)           // [MAXROWS][FFN]
{
  // XCD-grouped decomposition: expert = bid%8 (one expert per XCD), mt fastest within XCD.
  const int bid  = blockIdx.x;
  const int e    = bid & 7;
  const int slot = bid >> 3;            // 0..255
  const int mt   = slot & 15;
  const int nt   = slot >> 4;
  const int n = cnt[e];
  if (mt * 128 >= n) return;
  const int t = threadIdx.x;
  const int w = t >> 6, l = t & 63;

  __shared__ unsigned short Xs [128 * 64];
  __shared__ unsigned short W1s[128 * 64];
  __shared__ unsigned short W3s[128 * 64];
  __shared__ int stok[128];

  if (t < 128) {
    int idx = mt * 128 + t;
    stok[t] = tok[e * NTOK + min(idx, n - 1)];   // pad rows: duplicate last (masked later)
  }
  __syncthreads();

  const int r0 = t >> 3;                          // staged row (issue 1: +64)
  const size_t tok0 = (size_t)stok[r0];
  const size_t tok1 = (size_t)stok[64 + r0];
  const int kp = (((t & 7) ^ ((t >> 3) & 7)) << 3);  // pre-swizzled source unit offset (elems)

  const unsigned short* w1e = w1bf + (size_t)e * FFN_DIM * HIDDEN + (size_t)(nt * 128) * HIDDEN;
  const unsigned short* w3e = w3bf + (size_t)e * FFN_DIM * HIDDEN + (size_t)(nt * 128) * HIDDEN;

  f32x4 acc1[4][2], acc3[4][2];
#pragma unroll
  for (int i = 0; i < 4; ++i)
#pragma unroll
    for (int j = 0; j < 2; ++j) { acc1[i][j] = (f32x4)0.f; acc3[i][j] = (f32x4)0.f; }

  const int Moff = (w & 1) * 64;
  const int Noff = (w >> 1) * 32;
  const int lr = l & 15;                // fragment row-in-16
  const int lg = l >> 4;                // 0..3
  char* ldsX = (char*)Xs  + w * 1024;   // wave-uniform dest bases (lane adds l*16)
  char* ldsA = (char*)W1s + w * 1024;
  char* ldsB = (char*)W3s + w * 1024;

  for (int kb = 0; kb < HIDDEN / 64; ++kb) {
    __syncthreads();                    // previous compute done with LDS
    const int kofs = kb * 64 + kp;
    ld_g2l16(xbf + tok0 * HIDDEN + kofs,               ldsX);
    ld_g2l16(xbf + tok1 * HIDDEN + kofs,               ldsX + 8192);
    ld_g2l16(w1e + (size_t)r0 * HIDDEN + kofs,         ldsA);
    ld_g2l16(w1e + (size_t)(64 + r0) * HIDDEN + kofs,  ldsA + 8192);
    ld_g2l16(w3e + (size_t)r0 * HIDDEN + kofs,         ldsB);
    ld_g2l16(w3e + (size_t)(64 + r0) * HIDDEN + kofs,  ldsB + 8192);
    __syncthreads();                    // compiler drains vmcnt before s_barrier
#pragma unroll
    for (int s = 0; s < 2; ++s) {
      const int ug = 4 * s + lg;        // global k-unit this fragment wants
      bf16x8 a[4], b1[2], b3[2];
#pragma unroll
      for (int mi = 0; mi < 4; ++mi) {
        const int R = Moff + mi * 16 + lr;
        a[mi] = *(const bf16x8*)&Xs[R * 64 + ((ug ^ (lr & 7)) << 3)];
      }
#pragma unroll
      for (int ni = 0; ni < 2; ++ni) {
        const int R = Noff + ni * 16 + lr;
        b1[ni] = *(const bf16x8*)&W1s[R * 64 + ((ug ^ (lr & 7)) << 3)];
        b3[ni] = *(const bf16x8*)&W3s[R * 64 + ((ug ^ (lr & 7)) << 3)];
      }
#pragma unroll
      for (int mi = 0; mi < 4; ++mi)
#pragma unroll
        for (int ni = 0; ni < 2; ++ni) {
          acc1[mi][ni] = __builtin_amdgcn_mfma_f32_16x16x32_bf16(a[mi], b1[ni], acc1[mi][ni], 0, 0, 0);
          acc3[mi][ni] = __builtin_amdgcn_mfma_f32_16x16x32_bf16(a[mi], b3[ni], acc3[mi][ni], 0, 0, 0);
        }
    }
  }

  const size_t rbase = (size_t)base[e] + (size_t)mt * 128;
#pragma unroll
  for (int mi = 0; mi < 4; ++mi)
#pragma unroll
    for (int ni = 0; ni < 2; ++ni)
#pragma unroll
      for (int j = 0; j < 4; ++j) {
        int row = Moff + mi * 16 + lg * 4 + j;
        int col = nt * 128 + Noff + ni * 16 + lr;
        float s1 = acc1[mi][ni][j], s3 = acc3[mi][ni][j];
        float h = (s1 / (1.f + __expf(-s1))) * s3;      // silu(s1)*s3
        H[(rbase + row) * FFN_DIM + col] = f2bf(h);
      }
}

// ---------------- GEMM2: Y = H W2^T, scale by routing weight, atomicAdd into out ----------------
__global__ __launch_bounds__(512) void gemm2_kernel(
    const unsigned short* __restrict__ H,
    const unsigned short* __restrict__ w2bf,  // [E][HIDDEN][FFN]
    const int* __restrict__ cnt, const int* __restrict__ base,
    const int* __restrict__ tok, const float* __restrict__ wgt,
    float* __restrict__ out)
{
  const int bid  = blockIdx.x;
  const int e    = bid & 7;
  const int slot = bid >> 3;            // 0..127
  const int mt   = slot & 15;
  const int nt   = slot >> 4;           // 0..7
  const int n = cnt[e];
  if (mt * 128 >= n) return;
  const int t = threadIdx.x;
  const int w = t >> 6, l = t & 63;

  __shared__ unsigned short Hs[128 * 64];
  __shared__ unsigned short Ws[128 * 64];
  __shared__ int   stok[128];
  __shared__ float swgt[128];

  if (t < 128) {
    int idx = mt * 128 + t;
    int ok = idx < n;
    stok[t] = ok ? tok[e * NTOK + idx] : -1;
    swgt[t] = ok ? wgt[e * NTOK + idx] : 0.f;
  }

  const int r0 = t >> 3;
  const int kp = (((t & 7) ^ ((t >> 3) & 7)) << 3);
  const unsigned short* He  = H + (size_t)(base[e] + mt * 128) * FFN_DIM;
  const unsigned short* w2e = w2bf + (size_t)e * HIDDEN * FFN_DIM + (size_t)(nt * 128) * FFN_DIM;

  f32x4 acc[4][2];
#pragma unroll
  for (int i = 0; i < 4; ++i)
#pragma unroll
    for (int j = 0; j < 2; ++j) acc[i][j] = (f32x4)0.f;

  const int Moff = (w & 1) * 64;
  const int Noff = (w >> 1) * 32;
  const int lr = l & 15;
  const int lg = l >> 4;
  char* ldsH = (char*)Hs + w * 1024;
  char* ldsW = (char*)Ws + w * 1024;

  for (int kb = 0; kb < FFN_DIM / 64; ++kb) {
    __syncthreads();
    const int kofs = kb * 64 + kp;
    ld_g2l16(He  + (size_t)r0 * FFN_DIM + kofs,        ldsH);
    ld_g2l16(He  + (size_t)(64 + r0) * FFN_DIM + kofs, ldsH + 8192);
    ld_g2l16(w2e + (size_t)r0 * FFN_DIM + kofs,        ldsW);
    ld_g2l16(w2e + (size_t)(64 + r0) * FFN_DIM + kofs, ldsW + 8192);
    __syncthreads();
#pragma unroll
    for (int s = 0; s < 2; ++s) {
      const int ug = 4 * s + lg;
      bf16x8 a[4], b[2];
#pragma unroll
      for (int mi = 0; mi < 4; ++mi) {
        const int R = Moff + mi * 16 + lr;
        a[mi] = *(const bf16x8*)&Hs[R * 64 + ((ug ^ (lr & 7)) << 3)];
      }
#pragma unroll
      for (int ni = 0; ni < 2; ++ni) {
        const int R = Noff + ni * 16 + lr;
        b[ni] = *(const bf16x8*)&Ws[R * 64 + ((ug ^ (lr & 7)) << 3)];
      }
#pragma unroll
      for (int mi = 0; mi < 4; ++mi)
#pragma unroll
        for (int ni = 0; ni < 2; ++ni)
          acc[mi][ni] = __builtin_amdgcn_mfma_f32_16x16x32_bf16(a[mi], b[ni], acc[mi][ni], 0, 0, 0);
    }
  }

#pragma unroll
  for (int mi = 0; mi < 4; ++mi)
#pragma unroll
    for (int ni = 0; ni < 2; ++ni)
#pragma unroll
      for (int j = 0; j < 4; ++j) {
        int row = Moff + mi * 16 + lg * 4 + j;
        int tk = stok[row];
        if (tk >= 0) {
          int col = nt * 128 + Noff + ni * 16 + lr;
          atomicAdd(&out[(size_t)tk * HIDDEN + col], swgt[row] * acc[mi][ni][j]);
        }
      }
}

// ================= fp32 fallback path (used only if ws too small) =================
#define TT 12
#define FC 256
#define NCHUNK (FFN_DIM / FC)

__global__ __launch_bounds__(256) void moe_ffn_kernel(
    const float* __restrict__ x,
    const float* __restrict__ w1, const float* __restrict__ w2,
    const float* __restrict__ w3,
    const int* __restrict__ cnt, const int* __restrict__ tok,
    const float* __restrict__ wgt, float* __restrict__ out)
{
  const int e  = blockIdx.y;
  const int n  = cnt[e];
  const int ts = blockIdx.x * TT;
  if (ts >= n) return;
  const int tid = threadIdx.x;

  __shared__ float xs[TT * HIDDEN];
  __shared__ float hc[TT * FC];
  __shared__ int   stok[TT];
  __shared__ float swgt[TT];

  if (tid < TT) {
    int idx = ts + tid;
    int tk  = (idx < n) ? tok[e * NTOK + idx] : -1;
    stok[tid] = tk;
    swgt[tid] = (idx < n) ? wgt[e * NTOK + idx] : 0.f;
  }
  __syncthreads();
#pragma unroll
  for (int i = 0; i < TT; ++i) {
    int tk = stok[i];
    float4 v = make_float4(0.f, 0.f, 0.f, 0.f);
    if (tk >= 0) v = ((const float4*)(x + (size_t)tk * HIDDEN))[tid];
    ((float4*)(xs + i * HIDDEN))[tid] = v;
  }
  __syncthreads();

  const float* w1e = w1 + (size_t)e * FFN_DIM * HIDDEN;
  const float* w3e = w3 + (size_t)e * FFN_DIM * HIDDEN;
  const float* w2e = w2 + (size_t)e * HIDDEN * FFN_DIM;

  float yacc[4][TT];
#pragma unroll
  for (int j = 0; j < 4; ++j)
#pragma unroll
    for (int t = 0; t < TT; ++t) yacc[j][t] = 0.f;

  for (int c = 0; c < NCHUNK; ++c) {
    const int f = c * FC + tid;
    const float4* r1 = (const float4*)(w1e + (size_t)f * HIDDEN);
    const float4* r3 = (const float4*)(w3e + (size_t)f * HIDDEN);
    float a1[TT], a3[TT];
#pragma unroll
    for (int t = 0; t < TT; ++t) { a1[t] = 0.f; a3[t] = 0.f; }
    for (int k = 0; k < HIDDEN / 4; ++k) {
      float4 v1 = r1[k];
      float4 v3 = r3[k];
#pragma unroll
      for (int t = 0; t < TT; ++t) {
        float4 xv = *(const float4*)(xs + t * HIDDEN + 4 * k);
        a1[t] += xv.x * v1.x + xv.y * v1.y + xv.z * v1.z + xv.w * v1.w;
        a3[t] += xv.x * v3.x + xv.y * v3.y + xv.z * v3.z + xv.w * v3.w;
      }
    }
    __syncthreads();
#pragma unroll
    for (int t = 0; t < TT; ++t) {
      float g  = a1[t];
      float sg = g / (1.f + __expf(-g));
      hc[t * FC + tid] = sg * a3[t];
    }
    __syncthreads();
    const float4* r20 = (const float4*)(w2e + (size_t)(tid      ) * FFN_DIM + c * FC);
    const float4* r21 = (const float4*)(w2e + (size_t)(tid + 256) * FFN_DIM + c * FC);
    const float4* r22 = (const float4*)(w2e + (size_t)(tid + 512) * FFN_DIM + c * FC);
    const float4* r23 = (const float4*)(w2e + (size_t)(tid + 768) * FFN_DIM + c * FC);
    for (int k = 0; k < FC / 4; ++k) {
      float4 wv0 = r20[k], wv1 = r21[k], wv2 = r22[k], wv3 = r23[k];
#pragma unroll
      for (int t = 0; t < TT; ++t) {
        float4 hv = *(const float4*)(hc + t * FC + 4 * k);
        yacc[0][t] += hv.x * wv0.x + hv.y * wv0.y + hv.z * wv0.z + hv.w * wv0.w;
        yacc[1][t] += hv.x * wv1.x + hv.y * wv1.y + hv.z * wv1.z + hv.w * wv1.w;
        yacc[2][t] += hv.x * wv2.x + hv.y * wv2.y + hv.z * wv2.z + hv.w * wv2.w;
        yacc[3][t] += hv.x * wv3.x + hv.y * wv3.y + hv.z * wv3.z + hv.w * wv3.w;
      }
    }
  }

#pragma unroll
  for (int t = 0; t < TT; ++t) {
    int tk = stok[t];
    if (tk < 0) continue;
    float wt = swgt[t];
    float* orow = out + (size_t)tk * HIDDEN;
    atomicAdd(orow + tid,       wt * yacc[0][t]);
    atomicAdd(orow + tid + 256, wt * yacc[1][t]);
    atomicAdd(orow + tid + 512, wt * yacc[2][t]);
    atomicAdd(orow + tid + 768, wt * yacc[3][t]);
  }
}

extern "C" void kernel_launch(void* const* d_in, const int* in_sizes, int n_in,
                              void* d_out, int out_size, void* d_ws, size_t ws_size,
                              hipStream_t stream) {
  const float* x  = (const float*)d_in[0];
  const float* gw = (const float*)d_in[1];
  const float* w1 = (const float*)d_in[2];
  const float* w2 = (const float*)d_in[3];
  const float* w3 = (const float*)d_in[4];
  float* out    = (float*)d_out;
  float* logits = out + (size_t)NTOK * HIDDEN;

  char* ws = (char*)d_ws;
  int*   cnt  = (int*)(ws + OFF_CNT);
  int*   base = (int*)(ws + OFF_BASE);
  int*   tokp = (int*)(ws + OFF_TOK);
  float* wgtp = (float*)(ws + OFF_WGT);

  hipMemsetAsync(out, 0, (size_t)NTOK * HIDDEN * sizeof(float), stream);
  hipMemsetAsync(cnt, 0, NEXP * sizeof(int), stream);

  router_kernel<<<NTOK, 256, 0, stream>>>(x, gw, logits, cnt, tokp, wgtp);

  if (ws_size >= WS_NEED) {
    unsigned short* xbf  = (unsigned short*)(ws + OFF_XBF);
    unsigned short* w1bf = (unsigned short*)(ws + OFF_W1B);
    unsigned short* w3bf = (unsigned short*)(ws + OFF_W3B);
    unsigned short* w2bf = (unsigned short*)(ws + OFF_W2B);
    unsigned short* Hbuf = (unsigned short*)(ws + OFF_H);

    cvt_kernel<<<256, 256, 0, stream>>>(x, xbf, (int)(NTOK * HIDDEN / 4));
    cvt3_kernel<<<2048, 256, 0, stream>>>(w1, w3, w2, w1bf, w3bf, w2bf,
                                          (int)(NEXP * FFN_DIM * HIDDEN / 4));

    prefix_kernel<<<1, 64, 0, stream>>>(cnt, base);

    gemm1_kernel<<<NEXP * 16 * 16, 512, 0, stream>>>(xbf, w1bf, w3bf, cnt, base, tokp, Hbuf);
    gemm2_kernel<<<NEXP * 16 * 8, 512, 0, stream>>>(Hbuf, w2bf, cnt, base, tokp, wgtp, out);
  } else {
    dim3 grid((NTOK + TT - 1) / TT, NEXP);
    moe_ffn_kernel<<<grid, 256, 0, stream>>>(x, w1, w2, w3, cnt, tokp, wgtp, out);
  }
}